// Round 1
// baseline (15181.326 us; speedup 1.0000x reference)
//
#include <hip/hip_runtime.h>

#define NN   4096
#define OBSN 2048
#define S1   2047
#define S2   2047
#define HID  128
#define INDIM 100

// ---------- helpers ----------
__device__ __forceinline__ float sigm(float x) {
    return 1.0f / (1.0f + __expf(-x));
}
__device__ __forceinline__ float tanh_(float x) {
    float e = __expf(2.0f * x);
    return 1.0f - 2.0f / (e + 1.0f);
}

// Exact reference-semantics classification: in_x[i] = (gx[i] < x) && (x < gx[i+1]).
// a = #{j: bx[j] < x}, b = #{j: x < bx[j]}; valid iff a in [1,6] and a+b==7 (excludes
// exact-boundary equality, matching the strict-inequality reference).
__device__ __forceinline__ unsigned long long classify(float x, float y,
                                                       const float* bx, const float* by) {
    int a = 0, b = 0, c = 0, d = 0;
#pragma unroll
    for (int j = 0; j < 7; j++) {
        a += bx[j] < x;
        b += x < bx[j];
        c += by[j] < y;
        d += y < by[j];
    }
    if (a >= 1 && a <= 6 && (a + b) == 7 && c >= 1 && c <= 6 && (c + d) == 7)
        return 1ull << ((a - 1) * 6 + (c - 1));
    return 0ull;
}

// ---------- kernel 1: phase-1 occupancy masks (parallel over t) ----------
__global__ __launch_bounds__(256) void k_occ1(const float* __restrict__ obs,
                                              const float* __restrict__ oth,
                                              unsigned long long* __restrict__ occm) {
    const int t = blockIdx.x;      // step 0..2046, uses slice t+1, center observed[t+1]
    const int slice = t + 1;
    const float cx = obs[slice * 2 + 0];
    const float cy = obs[slice * 2 + 1];
    const float CST[7] = {-1.5f, -1.0f, -0.5f, 0.0f, 0.5f, 1.0f, 1.5f};
    float bx[7], by[7];
#pragma unroll
    for (int j = 0; j < 7; j++) { bx[j] = CST[j] + cx; by[j] = CST[j] + cy; }

    const float2* p = (const float2*)(oth + (size_t)slice * NN * 2);
    unsigned long long m = 0ull;
#pragma unroll 4
    for (int i = 0; i < 16; i++) {
        float2 q = p[i * 256 + threadIdx.x];
        if (q.x > bx[0] && q.x < bx[6] && q.y > by[0] && q.y < by[6])
            m |= classify(q.x, q.y, bx, by);
    }
#pragma unroll
    for (int off = 32; off > 0; off >>= 1) m |= __shfl_down(m, off);
    __shared__ unsigned long long sm[4];
    if ((threadIdx.x & 63) == 0) sm[threadIdx.x >> 6] = m;
    __syncthreads();
    if (threadIdx.x == 0) occm[t] = sm[0] | sm[1] | sm[2] | sm[3];
}

// ---------- kernel 2: transpose occupancy columns of W_ih into [36][512] ----------
__global__ void k_tr(const float* __restrict__ W_ih, float* __restrict__ WT) {
    WT[blockIdx.x * 512 + threadIdx.x] = W_ih[threadIdx.x * INDIM + 64 + blockIdx.x];
}

// ---------- kernel 3: phase-1 gate preactivation G1[t][512] (parallel over t) ----------
__global__ __launch_bounds__(256) void k_g1(const float* __restrict__ obs,
                                            const float* __restrict__ W_emb,
                                            const float* __restrict__ b_emb,
                                            const float* __restrict__ W_ih,
                                            const float* __restrict__ b_ih,
                                            const float* __restrict__ b_hh,
                                            const unsigned long long* __restrict__ occm,
                                            float* __restrict__ G1) {
    const int t = blockIdx.x;
    const int tid = threadIdx.x;
    __shared__ __align__(16) float e[64];
    const float d0 = obs[(t + 1) * 2 + 0] - obs[t * 2 + 0];
    const float d1 = obs[(t + 1) * 2 + 1] - obs[t * 2 + 1];
    if (tid < 64) {
        float v = W_emb[tid * 2 + 0] * d0 + W_emb[tid * 2 + 1] * d1 + b_emb[tid];
        e[tid] = v > 0.0f ? v : 0.0f;
    }
    __syncthreads();
    const unsigned long long m = occm[t];
#pragma unroll
    for (int rr = 0; rr < 2; rr++) {
        const int r = tid + rr * 256;
        const float* wr = W_ih + r * INDIM;
        float s = b_ih[r] + b_hh[r];
        float4 acc = {0.f, 0.f, 0.f, 0.f};
        const float4* w4 = (const float4*)wr;
        const float4* e4 = (const float4*)e;
#pragma unroll
        for (int q = 0; q < 16; q++) {
            float4 w = w4[q], ev = e4[q];
            acc.x += w.x * ev.x; acc.y += w.y * ev.y;
            acc.z += w.z * ev.z; acc.w += w.w * ev.w;
        }
        s += (acc.x + acc.y) + (acc.z + acc.w);
        unsigned long long mm = m;
        while (mm) {
            int j = __ffsll((long long)mm) - 1;
            mm &= mm - 1;
            s += wr[64 + j];
        }
        G1[t * 512 + r] = s;
    }
}

// ---------- kernel 4: the sequential LSTM (single workgroup, persistent) ----------
__global__ __launch_bounds__(256, 1) void k_seq(const float* __restrict__ obs,
                                                const float* __restrict__ oth,
                                                const float* __restrict__ W_emb,
                                                const float* __restrict__ b_emb,
                                                const float* __restrict__ W_ih,
                                                const float* __restrict__ b_ih,
                                                const float* __restrict__ W_hh,
                                                const float* __restrict__ b_hh,
                                                const float* __restrict__ W_out,
                                                const float* __restrict__ b_out,
                                                const float* __restrict__ G1,
                                                const float* __restrict__ WT,
                                                float* __restrict__ out) {
    const int tid = threadIdx.x;
    const int r0 = tid, r1 = tid + 256;

    // --- persistent register-resident weights ---
    float4 whh0[32], whh1[32], wie0[16], wie1[16];
#pragma unroll
    for (int q = 0; q < 32; q++) {
        whh0[q] = ((const float4*)(W_hh + r0 * HID))[q];
        whh1[q] = ((const float4*)(W_hh + r1 * HID))[q];
    }
#pragma unroll
    for (int q = 0; q < 16; q++) {
        wie0[q] = ((const float4*)(W_ih + r0 * INDIM))[q];
        wie1[q] = ((const float4*)(W_ih + r1 * INDIM))[q];
    }
    const float b20 = b_ih[r0] + b_hh[r0];
    const float b21 = b_ih[r1] + b_hh[r1];
    float wo0 = 0.f, wo1 = 0.f, wo2 = 0.f, wo3 = 0.f, wo4 = 0.f;
    if (tid < HID) {
        wo0 = W_out[0 * HID + tid]; wo1 = W_out[1 * HID + tid];
        wo2 = W_out[2 * HID + tid]; wo3 = W_out[3 * HID + tid];
        wo4 = W_out[4 * HID + tid];
    }
    const float bo0 = b_out[0], bo1 = b_out[1], bo2 = b_out[2], bo3 = b_out[3], bo4 = b_out[4];
    float we0 = 0.f, we1 = 0.f, be = 0.f;
    if (tid < 64) { we0 = W_emb[tid * 2]; we1 = W_emb[tid * 2 + 1]; be = b_emb[tid]; }

    __shared__ __align__(16) float h_lds[HID];
    __shared__ float sf[HID], so[HID];
    __shared__ __align__(16) float e_lds[64];
    __shared__ float red[2][5];
    __shared__ unsigned long long smask[4];
    __shared__ float posb[4];   // pp.x pp.y pc.x pc.y

    if (tid < HID) h_lds[tid] = 0.0f;
    float c = 0.0f;
    __syncthreads();

    float g1p0 = G1[r0], g1p1 = G1[r1];   // prefetch t=0

    // =============== phase 1 ===============
    for (int t = 0; t < S1; ++t) {
        float ga = g1p0, gb = g1p1;
        const int tn = (t + 1 < S1) ? t + 1 : t;
        g1p0 = G1[tn * 512 + r0];          // next-step prefetch (latency hidden)
        g1p1 = G1[tn * 512 + r1];

        float4 a0 = {0.f, 0.f, 0.f, 0.f}, a1 = {0.f, 0.f, 0.f, 0.f};
        const float4* h4 = (const float4*)h_lds;
#pragma unroll
        for (int q = 0; q < 32; q++) {
            float4 hv = h4[q];
            a0.x += whh0[q].x * hv.x; a0.y += whh0[q].y * hv.y;
            a0.z += whh0[q].z * hv.z; a0.w += whh0[q].w * hv.w;
            a1.x += whh1[q].x * hv.x; a1.y += whh1[q].y * hv.y;
            a1.z += whh1[q].z * hv.z; a1.w += whh1[q].w * hv.w;
        }
        ga += (a0.x + a0.y) + (a0.z + a0.w);
        gb += (a1.x + a1.y) + (a1.z + a1.w);

        float act0 = sigm(ga);                              // i (tid<128) or f
        float act1 = (tid < HID) ? tanh_(gb) : sigm(gb);    // gg or o
        if (tid >= HID) { sf[tid - HID] = act0; so[tid - HID] = act1; }
        __syncthreads();                                    // B1: sf/so ready; h reads done

        if (tid < HID) {
            c = sf[tid] * c + act0 * act1;
            float h = so[tid] * tanh_(c);
            h_lds[tid] = h;
            float p0 = wo0 * h, p1 = wo1 * h, p2 = wo2 * h, p3 = wo3 * h, p4 = wo4 * h;
#pragma unroll
            for (int off = 32; off > 0; off >>= 1) {
                p0 += __shfl_down(p0, off); p1 += __shfl_down(p1, off);
                p2 += __shfl_down(p2, off); p3 += __shfl_down(p3, off);
                p4 += __shfl_down(p4, off);
            }
            if (tid == 0)  { red[0][0] = p0; red[0][1] = p1; red[0][2] = p2; red[0][3] = p3; red[0][4] = p4; }
            if (tid == 64) { red[1][0] = p0; red[1][1] = p1; red[1][2] = p2; red[1][3] = p3; red[1][4] = p4; }
        }
        __syncthreads();                                    // B2: h_lds + red ready
        if (tid == 0) {
            float n0 = red[0][0] + red[1][0] + bo0;
            float n1 = red[0][1] + red[1][1] + bo1;
            float n2 = red[0][2] + red[1][2] + bo2;
            float n3 = red[0][3] + red[1][3] + bo3;
            float n4 = red[0][4] + red[1][4] + bo4;
            out[t * 5 + 0] = n0; out[t * 5 + 1] = n1; out[t * 5 + 2] = n2;
            out[t * 5 + 3] = n3; out[t * 5 + 4] = n4;
            if (t == S1 - 2) { posb[0] = obs[(t + 1) * 2] + n0; posb[1] = obs[(t + 1) * 2 + 1] + n1; }
            if (t == S1 - 1) { posb[2] = obs[(t + 1) * 2] + n0; posb[3] = obs[(t + 1) * 2 + 1] + n1; }
        }
    }
    __syncthreads();   // posb visible to all

    // =============== phase 2 ===============
    float4 nb[8];
    {
        const float4* p4 = (const float4*)(oth + (size_t)OBSN * NN * 2);
#pragma unroll
        for (int i = 0; i < 8; i++) nb[i] = p4[i * 256 + tid];
    }
    const float CST[7] = {-1.5f, -1.0f, -0.5f, 0.0f, 0.5f, 1.0f, 1.5f};

    for (int s = 0; s < S2; ++s) {
        const float ppx = posb[0], ppy = posb[1], pcx = posb[2], pcy = posb[3];
        float bx[7], by[7];
#pragma unroll
        for (int j = 0; j < 7; j++) { bx[j] = CST[j] + pcx; by[j] = CST[j] + pcy; }

        unsigned long long m = 0ull;
#pragma unroll
        for (int i = 0; i < 8; i++) {
            float4 q = nb[i];
            if (q.x > bx[0] && q.x < bx[6] && q.y > by[0] && q.y < by[6])
                m |= classify(q.x, q.y, bx, by);
            if (q.z > bx[0] && q.z < bx[6] && q.w > by[0] && q.w < by[6])
                m |= classify(q.z, q.w, bx, by);
        }
        {   // prefetch next neighbor slice (hidden behind this step's compute)
            const int sn = (s + 1 < S2) ? s + 1 : s;
            const float4* p4 = (const float4*)(oth + (size_t)(OBSN + sn) * NN * 2);
#pragma unroll
            for (int i = 0; i < 8; i++) nb[i] = p4[i * 256 + tid];
        }
#pragma unroll
        for (int off = 32; off > 0; off >>= 1) m |= __shfl_down(m, off);
        if ((tid & 63) == 0) smask[tid >> 6] = m;
        if (tid < 64) {
            float d0 = pcx - ppx, d1 = pcy - ppy;
            float v = we0 * d0 + we1 * d1 + be;
            e_lds[tid] = v > 0.0f ? v : 0.0f;
        }
        __syncthreads();                                    // Ba: smask + e_lds ready

        unsigned long long mm = smask[0] | smask[1] | smask[2] | smask[3];
        // issue occ-column loads early (consumed after the FMA block → latency hidden)
        float oa[6] = {0.f, 0.f, 0.f, 0.f, 0.f, 0.f};
        float ob[6] = {0.f, 0.f, 0.f, 0.f, 0.f, 0.f};
        unsigned long long m2 = mm;
#pragma unroll
        for (int i = 0; i < 6; i++) {
            if (m2) {
                int j = __ffsll((long long)m2) - 1;
                m2 &= m2 - 1;
                oa[i] = WT[j * 512 + r0];
                ob[i] = WT[j * 512 + r1];
            }
        }

        float ga = b20, gb = b21;
        {
            float4 a0 = {0.f, 0.f, 0.f, 0.f}, a1 = {0.f, 0.f, 0.f, 0.f};
            const float4* e4 = (const float4*)e_lds;
#pragma unroll
            for (int q = 0; q < 16; q++) {
                float4 ev = e4[q];
                a0.x += wie0[q].x * ev.x; a0.y += wie0[q].y * ev.y;
                a0.z += wie0[q].z * ev.z; a0.w += wie0[q].w * ev.w;
                a1.x += wie1[q].x * ev.x; a1.y += wie1[q].y * ev.y;
                a1.z += wie1[q].z * ev.z; a1.w += wie1[q].w * ev.w;
            }
            const float4* h4 = (const float4*)h_lds;
#pragma unroll
            for (int q = 0; q < 32; q++) {
                float4 hv = h4[q];
                a0.x += whh0[q].x * hv.x; a0.y += whh0[q].y * hv.y;
                a0.z += whh0[q].z * hv.z; a0.w += whh0[q].w * hv.w;
                a1.x += whh1[q].x * hv.x; a1.y += whh1[q].y * hv.y;
                a1.z += whh1[q].z * hv.z; a1.w += whh1[q].w * hv.w;
            }
            ga += (a0.x + a0.y) + (a0.z + a0.w);
            gb += (a1.x + a1.y) + (a1.z + a1.w);
        }
#pragma unroll
        for (int i = 0; i < 6; i++) { ga += oa[i]; gb += ob[i]; }
        while (m2) {   // rare: >6 occupied cells
            int j = __ffsll((long long)m2) - 1;
            m2 &= m2 - 1;
            ga += WT[j * 512 + r0];
            gb += WT[j * 512 + r1];
        }

        float act0 = sigm(ga);
        float act1 = (tid < HID) ? tanh_(gb) : sigm(gb);
        if (tid >= HID) { sf[tid - HID] = act0; so[tid - HID] = act1; }
        __syncthreads();                                    // Bb

        if (tid < HID) {
            c = sf[tid] * c + act0 * act1;
            float h = so[tid] * tanh_(c);
            h_lds[tid] = h;
            float p0 = wo0 * h, p1 = wo1 * h, p2 = wo2 * h, p3 = wo3 * h, p4 = wo4 * h;
#pragma unroll
            for (int off = 32; off > 0; off >>= 1) {
                p0 += __shfl_down(p0, off); p1 += __shfl_down(p1, off);
                p2 += __shfl_down(p2, off); p3 += __shfl_down(p3, off);
                p4 += __shfl_down(p4, off);
            }
            if (tid == 0)  { red[0][0] = p0; red[0][1] = p1; red[0][2] = p2; red[0][3] = p3; red[0][4] = p4; }
            if (tid == 64) { red[1][0] = p0; red[1][1] = p1; red[1][2] = p2; red[1][3] = p3; red[1][4] = p4; }
        }
        __syncthreads();                                    // Bc: h_lds + red ready
        if (tid == 0) {
            float n0 = red[0][0] + red[1][0] + bo0;
            float n1 = red[0][1] + red[1][1] + bo1;
            float n2 = red[0][2] + red[1][2] + bo2;
            float n3 = red[0][3] + red[1][3] + bo3;
            float n4 = red[0][4] + red[1][4] + bo4;
            const int row = S1 + s;
            out[row * 5 + 0] = n0; out[row * 5 + 1] = n1; out[row * 5 + 2] = n2;
            out[row * 5 + 3] = n3; out[row * 5 + 4] = n4;
            posb[0] = pcx; posb[1] = pcy;          // pp = pc
            posb[2] = pcx + n0; posb[3] = pcy + n1; // pc = pc + normal[:2]
        }
        __syncthreads();                                    // Bd: posb visible
    }
}

// ---------- launcher ----------
extern "C" void kernel_launch(void* const* d_in, const int* in_sizes, int n_in,
                              void* d_out, int out_size, void* d_ws, size_t ws_size,
                              hipStream_t stream) {
    const float* obs   = (const float*)d_in[0];
    const float* oth   = (const float*)d_in[1];
    const float* W_emb = (const float*)d_in[2];
    const float* b_emb = (const float*)d_in[3];
    const float* W_ih  = (const float*)d_in[4];
    const float* b_ih  = (const float*)d_in[5];
    const float* W_hh  = (const float*)d_in[6];
    const float* b_hh  = (const float*)d_in[7];
    const float* W_out = (const float*)d_in[8];
    const float* b_out = (const float*)d_in[9];
    float* out = (float*)d_out;

    unsigned long long* occm = (unsigned long long*)d_ws;               // 2047 u64 (pad to 16 KB)
    float* G1 = (float*)((char*)d_ws + 16384);                          // 2047*512 f32
    float* WT = (float*)((char*)d_ws + 16384 + (size_t)S1 * 512 * 4);   // 36*512 f32

    k_occ1<<<S1, 256, 0, stream>>>(obs, oth, occm);
    k_tr<<<36, 512, 0, stream>>>(W_ih, WT);
    k_g1<<<S1, 256, 0, stream>>>(obs, W_emb, b_emb, W_ih, b_ih, b_hh, occm, G1);
    k_seq<<<1, 256, 0, stream>>>(obs, oth, W_emb, b_emb, W_ih, b_ih, W_hh, b_hh,
                                 W_out, b_out, G1, WT, out);
}